// Round 10
// baseline (275.700 us; speedup 1.0000x reference)
//
#include <hip/hip_runtime.h>
#include <hip/hip_bf16.h>
#include <hip/hip_cooperative_groups.h>

namespace cg = cooperative_groups;

// Problem constants (B,S,H,P) = (512, 256, 768, 32)
#define B_  512
#define S_  256
#define H_  768
#define P_  32
#define K1_ 2304   // 3H
#define K2_ 1536   // 2H
#define N_  768
#define M_  512
#define NK1 72     // K1/32
#define NK2 48     // K2/32
#define NBLK 512   // cooperative grid
#define NCU 256    // MI355X
#define CVT_BLOCKS 512

typedef __attribute__((ext_vector_type(8))) short bf16x8v;
typedef __attribute__((ext_vector_type(8))) unsigned short u16x8;
typedef __attribute__((ext_vector_type(4))) float f32x4v;

__device__ inline unsigned short bfb(float x) {
  __hip_bfloat16 h = __float2bfloat16(x);  // RNE
  return *reinterpret_cast<unsigned short*>(&h);
}

// Fragment layout (bf16), MFMA 16x16x32 operand order (proven R2/R3):
//   frag[t16][k32][lane][8], lane = kg*16 + r; element (t,k):
//   t = t16*16 + r, k = k32*32 + kg*8 + e.
__device__ inline void store4_frag(__hip_bfloat16* __restrict__ buf, int NK,
                                   int m, int k, float4 v) {
  int m16 = m >> 4, mr = m & 15, k32 = k >> 5, kg = (k >> 3) & 3, e = k & 7;
  size_t off = ((size_t)(m16 * NK + k32) * 64 + kg * 16 + mr) * 8 + e;
  ushort4 u;
  u.x = bfb(v.x); u.y = bfb(v.y); u.z = bfb(v.z); u.w = bfb(v.w);
  *reinterpret_cast<ushort4*>(buf + off) = u;
}

// one 16B fragment-group of W conversion (fp32 row-major [n][k] -> B-frag)
__device__ inline void cvt_one(const float* __restrict__ W,
                               __hip_bfloat16* __restrict__ Wf,
                               int NK, int K, int gg) {
  int lane = gg & 63;
  int rest = gg >> 6;
  int k32 = rest % NK;
  int n16 = rest / NK;
  int n = n16 * 16 + (lane & 15);
  int k = k32 * 32 + (lane >> 4) * 8;
  const float4* sW = (const float4*)(W + (size_t)n * K + k);
  float4 v0 = sW[0], v1 = sW[1];
  u16x8 o;
  o[0] = bfb(v0.x); o[1] = bfb(v0.y); o[2] = bfb(v0.z); o[3] = bfb(v0.w);
  o[4] = bfb(v1.x); o[5] = bfb(v1.y); o[6] = bfb(v1.z); o[7] = bfb(v1.w);
  *reinterpret_cast<u16x8*>(Wf + (size_t)gg * 8) = o;
}

// ---------------------------------------------------------------------------
// GEMM per-wave body: 32x32 tile, frag-layout operands, d2 prefetch (R3/R8).
// ---------------------------------------------------------------------------
#define MFMA4(A0V, A1V, W0V, W1V)                                             \
  acc00 = __builtin_amdgcn_mfma_f32_16x16x32_bf16(A0V, W0V, acc00, 0, 0, 0);  \
  acc01 = __builtin_amdgcn_mfma_f32_16x16x32_bf16(A0V, W1V, acc01, 0, 0, 0);  \
  acc10 = __builtin_amdgcn_mfma_f32_16x16x32_bf16(A1V, W0V, acc10, 0, 0, 0);  \
  acc11 = __builtin_amdgcn_mfma_f32_16x16x32_bf16(A1V, W1V, acc11, 0, 0, 0);

template <int NK>
__device__ inline void gemm_body(const bf16x8v* __restrict__ Af,
                                 const bf16x8v* __restrict__ Wf,
                                 const float* __restrict__ bias,
                                 float* __restrict__ C, int mt, int nt) {
  const int lane = threadIdx.x & 63;

  const bf16x8v* A0 = Af + (size_t)(2 * mt) * NK * 64 + lane;
  const bf16x8v* A1 = A0 + (size_t)NK * 64;
  const bf16x8v* B0 = Wf + (size_t)(2 * nt) * NK * 64 + lane;
  const bf16x8v* B1 = B0 + (size_t)NK * 64;

  f32x4v acc00 = {0.f, 0.f, 0.f, 0.f};
  f32x4v acc01 = {0.f, 0.f, 0.f, 0.f};
  f32x4v acc10 = {0.f, 0.f, 0.f, 0.f};
  f32x4v acc11 = {0.f, 0.f, 0.f, 0.f};

  bf16x8v a0s0 = A0[0],  a1s0 = A1[0],  w0s0 = B0[0],  w1s0 = B1[0];
  bf16x8v a0s1 = A0[64], a1s1 = A1[64], w0s1 = B0[64], w1s1 = B1[64];

  for (int k = 0; k < NK - 2; k += 2) {
    bf16x8v pa0 = A0[(size_t)(k + 2) * 64];
    bf16x8v pa1 = A1[(size_t)(k + 2) * 64];
    bf16x8v pw0 = B0[(size_t)(k + 2) * 64];
    bf16x8v pw1 = B1[(size_t)(k + 2) * 64];
    bf16x8v qa0 = A0[(size_t)(k + 3) * 64];
    bf16x8v qa1 = A1[(size_t)(k + 3) * 64];
    bf16x8v qw0 = B0[(size_t)(k + 3) * 64];
    bf16x8v qw1 = B1[(size_t)(k + 3) * 64];
    MFMA4(a0s0, a1s0, w0s0, w1s0)
    MFMA4(a0s1, a1s1, w0s1, w1s1)
    a0s0 = pa0; a1s0 = pa1; w0s0 = pw0; w1s0 = pw1;
    a0s1 = qa0; a1s1 = qa1; w0s1 = qw0; w1s1 = qw1;
  }
  MFMA4(a0s0, a1s0, w0s0, w1s0)
  MFMA4(a0s1, a1s1, w0s1, w1s1)

  // C/D layout: col = lane&15, row = (lane>>4)*4 + j  (verified R2)
  const int m0 = mt * 32, n0 = nt * 32;
  const int col = lane & 15;
  const int rg = (lane >> 4) * 4;
  const float bv0 = bias[n0 + col];
  const float bv1 = bias[n0 + 16 + col];
#pragma unroll
  for (int j = 0; j < 4; ++j) {
    const int r = rg + j;
    C[(size_t)(m0 + r) * N_ + n0 + col]           = acc00[j] + bv0;
    C[(size_t)(m0 + r) * N_ + n0 + 16 + col]      = acc01[j] + bv1;
    C[(size_t)(m0 + 16 + r) * N_ + n0 + col]      = acc10[j] + bv0;
    C[(size_t)(m0 + 16 + r) * N_ + n0 + 16 + col] = acc11[j] + bv1;
  }
}

// ---------------------------------------------------------------------------
// Cooperative fused kernel: pool+cvt | grid.sync | GEMM | grid.sync | norm.
// __launch_bounds__(256,2): cap VGPR so 2 blocks/CU -> 512 blocks co-resident.
// ---------------------------------------------------------------------------
__global__ __launch_bounds__(256, 2) void fused_kernel(
    const float* __restrict__ phys, const float* __restrict__ proc,
    const float* __restrict__ micro, const int* __restrict__ pos,
    const float* __restrict__ W1, const float* __restrict__ b1,
    const float* __restrict__ W2, const float* __restrict__ b2,
    __hip_bfloat16* __restrict__ A1f, __hip_bfloat16* __restrict__ A2f,
    __hip_bfloat16* __restrict__ W1f, __hip_bfloat16* __restrict__ W2f,
    float* __restrict__ out) {
  cg::grid_group grid = cg::this_grid();
  const int t = threadIdx.x;
  const int bid = blockIdx.x;   // == batch for pool phase

  // ===== Phase 1: pool (waves 0-2) + W1 cvt (wave 3), then W2 cvt (all) ====
  __shared__ int sp[P_];
  __shared__ int scnt;
  if (t < 64) {  // wave 0 compacts valid positions of batch `bid`
    int p = (t < P_) ? pos[bid * P_ + t] : -1;
    bool valid = (p != -1);
    unsigned long long m = __ballot(valid);
    int pre = __popcll(m & ((1ull << t) - 1ull));
    if (valid) sp[pre] = p;
    if (t == 0) scnt = (int)__popcll(m);
  }
  __syncthreads();

  if (t < 192) {
    // ---- pool BOTH tensors for batch `bid`; 4-deep, 8 loads in flight ----
    const int c = scnt;  // >= 1
    const float inv = 1.0f / (float)c;
    const int H4 = H_ / 4;  // 192
    const float4* pb = (const float4*)(proc  + (size_t)bid * S_ * H_);
    const float4* mb = (const float4*)(micro + (size_t)bid * S_ * H_);

    float4 sentp = pb[t];   // proc row 0 (issued early)
    float4 sentm = mb[t];   // micro row 0
    float4 sph = ((const float4*)(phys + (size_t)bid * S_ * H_))[t];

    float4 ap = {0,0,0,0}, am = {0,0,0,0};
    int i = 0;
    for (; i + 4 <= c; i += 4) {
      int x0 = sp[i], x1 = sp[i+1], x2 = sp[i+2], x3 = sp[i+3];
      float4 p0 = pb[(size_t)x0*H4 + t]; float4 q0 = mb[(size_t)x0*H4 + t];
      float4 p1 = pb[(size_t)x1*H4 + t]; float4 q1 = mb[(size_t)x1*H4 + t];
      float4 p2 = pb[(size_t)x2*H4 + t]; float4 q2 = mb[(size_t)x2*H4 + t];
      float4 p3 = pb[(size_t)x3*H4 + t]; float4 q3 = mb[(size_t)x3*H4 + t];
      ap.x += p0.x+p1.x+p2.x+p3.x;  am.x += q0.x+q1.x+q2.x+q3.x;
      ap.y += p0.y+p1.y+p2.y+p3.y;  am.y += q0.y+q1.y+q2.y+q3.y;
      ap.z += p0.z+p1.z+p2.z+p3.z;  am.z += q0.z+q1.z+q2.z+q3.z;
      ap.w += p0.w+p1.w+p2.w+p3.w;  am.w += q0.w+q1.w+q2.w+q3.w;
    }
    for (; i < c; ++i) {
      int x = sp[i];
      float4 p = pb[(size_t)x*H4 + t]; float4 q = mb[(size_t)x*H4 + t];
      ap.x += p.x; ap.y += p.y; ap.z += p.z; ap.w += p.w;
      am.x += q.x; am.y += q.y; am.z += q.z; am.w += q.w;
    }
    float4 pooled_p = make_float4(ap.x*inv, ap.y*inv, ap.z*inv, ap.w*inv);
    float4 pooled_m = make_float4(am.x*inv, am.y*inv, am.z*inv, am.w*inv);
    const int k = t * 4;
    store4_frag(A1f, NK1, bid, k,          pooled_p);
    store4_frag(A1f, NK1, bid, k + H_,     sentp);
    store4_frag(A1f, NK1, bid, k + 2*H_,   sph);
    store4_frag(A2f, NK2, bid, k,          pooled_m);
    store4_frag(A2f, NK2, bid, k + H_,     sentm);
  } else {
    // ---- wave 3: convert ALL of W1 (overlapped under pooling) ----
    const int NG1 = 48 * NK1 * 64;  // 221184
    for (int g = bid * 64 + (t - 192); g < NG1; g += NBLK * 64)
      cvt_one(W1, W1f, NK1, K1_, g);
  }
  // ---- all threads: convert W2 ----
  {
    const int NG2 = 48 * NK2 * 64;  // 147456
    for (int g = bid * 256 + t; g < NG2; g += NBLK * 256)
      cvt_one(W2, W2f, NK2, K2_, g);
  }
  __threadfence();
  grid.sync();

  // ===== Phase 2: dual GEMM, 768 wave-tiles over 512 blocks ================
  {
    const int wid = t >> 6;
    int pr = -1, half = 0;
    if (bid < 256) {
      if (wid < 2) { pr = bid; half = wid; }
    } else {
      int s = bid - 256;
      if (wid == 0) { pr = 256 + (s >> 1); half = s & 1; }
    }
    if (pr >= 0) {
      const int g = (pr >= 192);
      const int prl = g ? pr - 192 : pr;
      const int mt = prl / 12;
      const int nt = (prl % 12) * 2 + half;
      if (!g)
        gemm_body<NK1>((const bf16x8v*)A1f, (const bf16x8v*)W1f, b1, out, mt, nt);
      else
        gemm_body<NK2>((const bf16x8v*)A2f, (const bf16x8v*)W2f, b2,
                       out + (size_t)M_ * N_, mt, nt);
    }
  }
  __threadfence();
  grid.sync();

  // ===== Phase 3: row L2 norm, 2 rows per block ============================
  __shared__ float ws[4];
  for (int row = bid; row < 2 * B_; row += NBLK) {
    float* p = out + (size_t)row * N_;
    float x0 = p[t];
    float x1 = p[t + 256];
    float x2 = p[t + 512];
    float s = x0*x0 + x1*x1 + x2*x2;
#pragma unroll
    for (int off = 32; off > 0; off >>= 1) s += __shfl_down(s, off);
    const int lane = t & 63, wv = t >> 6;
    if (lane == 0) ws[wv] = s;
    __syncthreads();
    float tot = ws[0] + ws[1] + ws[2] + ws[3];
    float inv = 1.0f / fmaxf(sqrtf(tot), 1e-12f);
    p[t]       = x0 * inv;
    p[t + 256] = x1 * inv;
    p[t + 512] = x2 * inv;
    __syncthreads();  // ws reuse across iterations
  }
}

// ---------------------------------------------------------------------------
// Fallback path (R8, proven 45.4 us): pool+cvt | gemm | norm as 3 kernels.
// ---------------------------------------------------------------------------
__global__ __launch_bounds__(192) void pool_cvt_kernel(
    const float* __restrict__ phys, const float* __restrict__ proc,
    const float* __restrict__ micro, const int* __restrict__ pos,
    const float* __restrict__ W1, const float* __restrict__ W2,
    __hip_bfloat16* __restrict__ A1f, __hip_bfloat16* __restrict__ A2f,
    __hip_bfloat16* __restrict__ W1f, __hip_bfloat16* __restrict__ W2f) {
  const int t = threadIdx.x;  // 0..191
  const int NPOOL = 2 * B_;   // 1024
  if (blockIdx.x < NPOOL) {
    const int bid = blockIdx.x;
    const int b   = bid >> 1;
    const int sel = bid & 1;

    __shared__ int sp[P_];
    __shared__ int scnt;
    if (t < 64) {
      int p = (t < P_) ? pos[b * P_ + t] : -1;
      bool valid = (p != -1);
      unsigned long long m = __ballot(valid);
      int pre = __popcll(m & ((1ull << t) - 1ull));
      if (valid) sp[pre] = p;
      if (t == 0) scnt = (int)__popcll(m);
    }
    __syncthreads();
    const int c = scnt;
    const float inv = 1.0f / (float)c;

    const int H4 = H_ / 4;
    const float* base = (sel == 0) ? proc : micro;
    const float4* srcb = (const float4*)(base + (size_t)b * S_ * H_);

    float4 sent = srcb[t];
    float4 sph = make_float4(0.f, 0.f, 0.f, 0.f);
    if (sel == 0) sph = ((const float4*)(phys + (size_t)b * S_ * H_))[t];

    float4 s0 = make_float4(0.f, 0.f, 0.f, 0.f);
    float4 s1 = make_float4(0.f, 0.f, 0.f, 0.f);
    int i = 0;
    for (; i + 8 <= c; i += 8) {
      float4 v0 = srcb[(size_t)sp[i+0] * H4 + t];
      float4 v1 = srcb[(size_t)sp[i+1] * H4 + t];
      float4 v2 = srcb[(size_t)sp[i+2] * H4 + t];
      float4 v3 = srcb[(size_t)sp[i+3] * H4 + t];
      float4 v4 = srcb[(size_t)sp[i+4] * H4 + t];
      float4 v5 = srcb[(size_t)sp[i+5] * H4 + t];
      float4 v6 = srcb[(size_t)sp[i+6] * H4 + t];
      float4 v7 = srcb[(size_t)sp[i+7] * H4 + t];
      s0.x += v0.x + v1.x + v2.x + v3.x;  s1.x += v4.x + v5.x + v6.x + v7.x;
      s0.y += v0.y + v1.y + v2.y + v3.y;  s1.y += v4.y + v5.y + v6.y + v7.y;
      s0.z += v0.z + v1.z + v2.z + v3.z;  s1.z += v4.z + v5.z + v6.z + v7.z;
      s0.w += v0.w + v1.w + v2.w + v3.w;  s1.w += v4.w + v5.w + v6.w + v7.w;
    }
    for (; i + 2 <= c; i += 2) {
      float4 v0 = srcb[(size_t)sp[i+0] * H4 + t];
      float4 v1 = srcb[(size_t)sp[i+1] * H4 + t];
      s0.x += v0.x + v1.x; s0.y += v0.y + v1.y;
      s0.z += v0.z + v1.z; s0.w += v0.w + v1.w;
    }
    if (i < c) {
      float4 v = srcb[(size_t)sp[i] * H4 + t];
      s0.x += v.x; s0.y += v.y; s0.z += v.z; s0.w += v.w;
    }
    float4 pooled = make_float4((s0.x + s1.x) * inv, (s0.y + s1.y) * inv,
                                (s0.z + s1.z) * inv, (s0.w + s1.w) * inv);

    const int k = t * 4;
    if (sel == 0) {
      store4_frag(A1f, NK1, b, k,          pooled);
      store4_frag(A1f, NK1, b, k + H_,     sent);
      store4_frag(A1f, NK1, b, k + 2*H_,   sph);
    } else {
      store4_frag(A2f, NK2, b, k,          pooled);
      store4_frag(A2f, NK2, b, k + H_,     sent);
    }
  } else {
    const int NG1 = 48 * NK1 * 64;
    const int NG2 = 48 * NK2 * 64;
    int tid = (blockIdx.x - NPOOL) * 192 + t;
    const int stride = CVT_BLOCKS * 192;
    for (int g = tid; g < NG1 + NG2; g += stride) {
      if (g < NG1) cvt_one(W1, W1f, NK1, K1_, g);
      else         cvt_one(W2, W2f, NK2, K2_, g - NG1);
    }
  }
}

__global__ __launch_bounds__(256) void gemm_mfma_kernel(
    const __hip_bfloat16* __restrict__ A1f, const __hip_bfloat16* __restrict__ A2f,
    const __hip_bfloat16* __restrict__ W1f, const __hip_bfloat16* __restrict__ W2f,
    const float* __restrict__ b1, const float* __restrict__ b2,
    float* __restrict__ out) {
  const int bid = blockIdx.x;
  const int x = bid & 7;
  const int local = bid >> 3;
  const int ntb_g = x * 3 + local % 3;
  const int mtb = local / 3;
  const int wid = threadIdx.x >> 6;
  const int wr = wid >> 1, wc = wid & 1;
  const int mt = mtb * 2 + wr;
  if (ntb_g < 12) {
    const int nt = ntb_g * 2 + wc;
    gemm_body<NK1>((const bf16x8v*)A1f, (const bf16x8v*)W1f, b1, out, mt, nt);
  } else {
    const int nt = (ntb_g - 12) * 2 + wc;
    gemm_body<NK2>((const bf16x8v*)A2f, (const bf16x8v*)W2f, b2,
                   out + (size_t)M_ * N_, mt, nt);
  }
}

__global__ __launch_bounds__(256) void norm_rows_kernel(float* __restrict__ out) {
  const int row = blockIdx.x;
  float* p = out + (size_t)row * N_;
  const int t = threadIdx.x;
  float x0 = p[t];
  float x1 = p[t + 256];
  float x2 = p[t + 512];
  float s = x0*x0 + x1*x1 + x2*x2;
#pragma unroll
  for (int off = 32; off > 0; off >>= 1) s += __shfl_down(s, off);
  __shared__ float ws[4];
  const int lane = t & 63, wid = t >> 6;
  if (lane == 0) ws[wid] = s;
  __syncthreads();
  float tot = ws[0] + ws[1] + ws[2] + ws[3];
  float inv = 1.0f / fmaxf(sqrtf(tot), 1e-12f);
  p[t]       = x0 * inv;
  p[t + 256] = x1 * inv;
  p[t + 512] = x2 * inv;
}

// ---------------------------------------------------------------------------
extern "C" void kernel_launch(void* const* d_in, const int* in_sizes, int n_in,
                              void* d_out, int out_size, void* d_ws, size_t ws_size,
                              hipStream_t stream) {
  const float* phys  = (const float*)d_in[0];
  const float* proc  = (const float*)d_in[1];
  const float* micro = (const float*)d_in[2];
  const int*   pos   = (const int*)d_in[3];
  const float* W1    = (const float*)d_in[4];
  const float* b1    = (const float*)d_in[5];
  const float* W2    = (const float*)d_in[6];
  const float* b2    = (const float*)d_in[7];
  float* out = (float*)d_out;

  __hip_bfloat16* A1f = (__hip_bfloat16*)d_ws;
  __hip_bfloat16* A2f = A1f + (size_t)32 * NK1 * 512;
  __hip_bfloat16* W1f = A2f + (size_t)32 * NK2 * 512;
  __hip_bfloat16* W2f = W1f + (size_t)48 * NK1 * 512;

  // Host-side occupancy precheck (capture-safe): cooperative launch only if
  // 512 blocks are provably co-resident for this kernel.
  int blocksPerCU = 0;
  hipError_t occErr = hipOccupancyMaxActiveBlocksPerMultiprocessor(
      &blocksPerCU, (const void*)fused_kernel, 256, 0);
  bool coop_ok = (occErr == hipSuccess) && (blocksPerCU * NCU >= NBLK);

  if (coop_ok) {
    void* args[] = {
        (void*)&phys, (void*)&proc, (void*)&micro, (void*)&pos,
        (void*)&W1, (void*)&b1, (void*)&W2, (void*)&b2,
        (void*)&A1f, (void*)&A2f, (void*)&W1f, (void*)&W2f, (void*)&out};
    hipError_t e = hipLaunchCooperativeKernel((void*)fused_kernel, dim3(NBLK),
                                              dim3(256), args, 0, stream);
    if (e == hipSuccess) return;
    (void)hipGetLastError();  // clear sticky error, fall through
  }

  // Fallback: proven R8 three-kernel path.
  pool_cvt_kernel<<<2 * B_ + CVT_BLOCKS, 192, 0, stream>>>(
      phys, proc, micro, pos, W1, W2, A1f, A2f, W1f, W2f);
  gemm_mfma_kernel<<<192, 256, 0, stream>>>(
      A1f, A2f, W1f, W2f, b1, b2, out);
  norm_rows_kernel<<<2 * B_, 256, 0, stream>>>(out);
}

// Round 11
// 51.140 us; speedup vs baseline: 5.3911x; 5.3911x over previous
//
#include <hip/hip_runtime.h>
#include <hip/hip_bf16.h>

// Problem constants (B,S,H,P) = (512, 256, 768, 32)
#define B_  512
#define S_  256
#define H_  768
#define P_  32
#define K1_ 2304   // 3H
#define K2_ 1536   // 2H
#define N_  768
#define M_  512
#define NK1 72     // K1/32
#define NK2 48     // K2/32
#define CVT_BLOCKS 512

typedef __attribute__((ext_vector_type(8))) short bf16x8v;
typedef __attribute__((ext_vector_type(8))) unsigned short u16x8;
typedef __attribute__((ext_vector_type(4))) float f32x4v;

__device__ inline unsigned short bfb(float x) {
  __hip_bfloat16 h = __float2bfloat16(x);  // RNE
  return *reinterpret_cast<unsigned short*>(&h);
}

// Fragment layout (bf16), MFMA 16x16x32 operand order (proven R2/R3):
//   frag[t16][k32][lane][8], lane = kg*16 + r; element (t,k):
//   t = t16*16 + r, k = k32*32 + kg*8 + e.
__device__ inline void store4_frag(__hip_bfloat16* __restrict__ buf, int NK,
                                   int m, int k, float4 v) {
  int m16 = m >> 4, mr = m & 15, k32 = k >> 5, kg = (k >> 3) & 3, e = k & 7;
  size_t off = ((size_t)(m16 * NK + k32) * 64 + kg * 16 + mr) * 8 + e;
  ushort4 u;
  u.x = bfb(v.x); u.y = bfb(v.y); u.z = bfb(v.z); u.w = bfb(v.w);
  *reinterpret_cast<ushort4*>(buf + off) = u;
}

// one 16B fragment-group of W conversion (fp32 row-major [n][k] -> B-frag)
__device__ inline void cvt_one(const float* __restrict__ W,
                               __hip_bfloat16* __restrict__ Wf,
                               int NK, int K, int gg) {
  int lane = gg & 63;
  int rest = gg >> 6;
  int k32 = rest % NK;
  int n16 = rest / NK;
  int n = n16 * 16 + (lane & 15);
  int k = k32 * 32 + (lane >> 4) * 8;
  const float4* sW = (const float4*)(W + (size_t)n * K + k);
  float4 v0 = sW[0], v1 = sW[1];
  u16x8 o;
  o[0] = bfb(v0.x); o[1] = bfb(v0.y); o[2] = bfb(v0.z); o[3] = bfb(v0.w);
  o[4] = bfb(v1.x); o[5] = bfb(v1.y); o[6] = bfb(v1.z); o[7] = bfb(v1.w);
  *reinterpret_cast<u16x8*>(Wf + (size_t)gg * 8) = o;
}

// ---------------------------------------------------------------------------
// Kernel 1 (R8 structure): blocks [0,2B): (batch,tensor) mean-pool -> A-frag.
// blocks [2B,2B+CVT_BLOCKS): W cvt (grid-stride). First cvt block also zeroes
// the 16 row-group counters (handles the harness's 0xAA ws poison; kernel
// boundary release/acquire makes the zeros visible to kernel 2).
// ---------------------------------------------------------------------------
__global__ __launch_bounds__(192) void pool_cvt_kernel(
    const float* __restrict__ phys, const float* __restrict__ proc,
    const float* __restrict__ micro, const int* __restrict__ pos,
    const float* __restrict__ W1, const float* __restrict__ W2,
    __hip_bfloat16* __restrict__ A1f, __hip_bfloat16* __restrict__ A2f,
    __hip_bfloat16* __restrict__ W1f, __hip_bfloat16* __restrict__ W2f,
    int* __restrict__ cnt) {
  const int t = threadIdx.x;  // 0..191
  const int NPOOL = 2 * B_;   // 1024
  if (blockIdx.x < NPOOL) {
    const int bid = blockIdx.x;
    const int b   = bid >> 1;
    const int sel = bid & 1;

    __shared__ int sp[P_];
    __shared__ int scnt;
    if (t < 64) {
      int p = (t < P_) ? pos[b * P_ + t] : -1;
      bool valid = (p != -1);
      unsigned long long m = __ballot(valid);
      int pre = __popcll(m & ((1ull << t) - 1ull));
      if (valid) sp[pre] = p;
      if (t == 0) scnt = (int)__popcll(m);
    }
    __syncthreads();
    const int c = scnt;  // >= 1
    const float inv = 1.0f / (float)c;

    const int H4 = H_ / 4;
    const float* base = (sel == 0) ? proc : micro;
    const float4* srcb = (const float4*)(base + (size_t)b * S_ * H_);

    float4 sent = srcb[t];
    float4 sph = make_float4(0.f, 0.f, 0.f, 0.f);
    if (sel == 0) sph = ((const float4*)(phys + (size_t)b * S_ * H_))[t];

    float4 s0 = make_float4(0.f, 0.f, 0.f, 0.f);
    float4 s1 = make_float4(0.f, 0.f, 0.f, 0.f);
    int i = 0;
    for (; i + 8 <= c; i += 8) {
      float4 v0 = srcb[(size_t)sp[i+0] * H4 + t];
      float4 v1 = srcb[(size_t)sp[i+1] * H4 + t];
      float4 v2 = srcb[(size_t)sp[i+2] * H4 + t];
      float4 v3 = srcb[(size_t)sp[i+3] * H4 + t];
      float4 v4 = srcb[(size_t)sp[i+4] * H4 + t];
      float4 v5 = srcb[(size_t)sp[i+5] * H4 + t];
      float4 v6 = srcb[(size_t)sp[i+6] * H4 + t];
      float4 v7 = srcb[(size_t)sp[i+7] * H4 + t];
      s0.x += v0.x + v1.x + v2.x + v3.x;  s1.x += v4.x + v5.x + v6.x + v7.x;
      s0.y += v0.y + v1.y + v2.y + v3.y;  s1.y += v4.y + v5.y + v6.y + v7.y;
      s0.z += v0.z + v1.z + v2.z + v3.z;  s1.z += v4.z + v5.z + v6.z + v7.z;
      s0.w += v0.w + v1.w + v2.w + v3.w;  s1.w += v4.w + v5.w + v6.w + v7.w;
    }
    for (; i + 2 <= c; i += 2) {
      float4 v0 = srcb[(size_t)sp[i+0] * H4 + t];
      float4 v1 = srcb[(size_t)sp[i+1] * H4 + t];
      s0.x += v0.x + v1.x; s0.y += v0.y + v1.y;
      s0.z += v0.z + v1.z; s0.w += v0.w + v1.w;
    }
    if (i < c) {
      float4 v = srcb[(size_t)sp[i] * H4 + t];
      s0.x += v.x; s0.y += v.y; s0.z += v.z; s0.w += v.w;
    }
    float4 pooled = make_float4((s0.x + s1.x) * inv, (s0.y + s1.y) * inv,
                                (s0.z + s1.z) * inv, (s0.w + s1.w) * inv);

    const int k = t * 4;
    if (sel == 0) {
      store4_frag(A1f, NK1, b, k,          pooled);
      store4_frag(A1f, NK1, b, k + H_,     sent);
      store4_frag(A1f, NK1, b, k + 2*H_,   sph);
    } else {
      store4_frag(A2f, NK2, b, k,          pooled);
      store4_frag(A2f, NK2, b, k + H_,     sent);
    }
  } else {
    if (blockIdx.x == NPOOL && t < 16) cnt[t] = 0;  // counters for kernel 2
    const int NG1 = 48 * NK1 * 64;
    const int NG2 = 48 * NK2 * 64;
    int tid = (blockIdx.x - NPOOL) * 192 + t;
    const int stride = CVT_BLOCKS * 192;
    for (int g = tid; g < NG1 + NG2; g += stride) {
      if (g < NG1) cvt_one(W1, W1f, NK1, K1_, g);
      else         cvt_one(W2, W2f, NK2, K2_, g - NG1);
    }
  }
}

// ---------------------------------------------------------------------------
// Kernel 2: dual bf16 MFMA GEMM (R8 4-wave 64x64 blocks, frag operands, d2
// prefetch) + FUSED L2-norm: C stored with agent-scope (IC-coherent) stores;
// per-64-row-group counter; the 12th (last) column-block normalizes its rows.
// ---------------------------------------------------------------------------
#define MFMA4(A0V, A1V, W0V, W1V)                                             \
  acc00 = __builtin_amdgcn_mfma_f32_16x16x32_bf16(A0V, W0V, acc00, 0, 0, 0);  \
  acc01 = __builtin_amdgcn_mfma_f32_16x16x32_bf16(A0V, W1V, acc01, 0, 0, 0);  \
  acc10 = __builtin_amdgcn_mfma_f32_16x16x32_bf16(A1V, W0V, acc10, 0, 0, 0);  \
  acc11 = __builtin_amdgcn_mfma_f32_16x16x32_bf16(A1V, W1V, acc11, 0, 0, 0);

template <int NK>
__device__ inline void gemm_body(const bf16x8v* __restrict__ Af,
                                 const bf16x8v* __restrict__ Wf,
                                 const float* __restrict__ bias,
                                 float* __restrict__ C, int mt, int nt) {
  const int lane = threadIdx.x & 63;

  const bf16x8v* A0 = Af + (size_t)(2 * mt) * NK * 64 + lane;
  const bf16x8v* A1 = A0 + (size_t)NK * 64;
  const bf16x8v* B0 = Wf + (size_t)(2 * nt) * NK * 64 + lane;
  const bf16x8v* B1 = B0 + (size_t)NK * 64;

  f32x4v acc00 = {0.f, 0.f, 0.f, 0.f};
  f32x4v acc01 = {0.f, 0.f, 0.f, 0.f};
  f32x4v acc10 = {0.f, 0.f, 0.f, 0.f};
  f32x4v acc11 = {0.f, 0.f, 0.f, 0.f};

  bf16x8v a0s0 = A0[0],  a1s0 = A1[0],  w0s0 = B0[0],  w1s0 = B1[0];
  bf16x8v a0s1 = A0[64], a1s1 = A1[64], w0s1 = B0[64], w1s1 = B1[64];

  for (int k = 0; k < NK - 2; k += 2) {
    bf16x8v pa0 = A0[(size_t)(k + 2) * 64];
    bf16x8v pa1 = A1[(size_t)(k + 2) * 64];
    bf16x8v pw0 = B0[(size_t)(k + 2) * 64];
    bf16x8v pw1 = B1[(size_t)(k + 2) * 64];
    bf16x8v qa0 = A0[(size_t)(k + 3) * 64];
    bf16x8v qa1 = A1[(size_t)(k + 3) * 64];
    bf16x8v qw0 = B0[(size_t)(k + 3) * 64];
    bf16x8v qw1 = B1[(size_t)(k + 3) * 64];
    MFMA4(a0s0, a1s0, w0s0, w1s0)
    MFMA4(a0s1, a1s1, w0s1, w1s1)
    a0s0 = pa0; a1s0 = pa1; w0s0 = pw0; w1s0 = pw1;
    a0s1 = qa0; a1s1 = qa1; w0s1 = qw0; w1s1 = qw1;
  }
  MFMA4(a0s0, a1s0, w0s0, w1s0)
  MFMA4(a0s1, a1s1, w0s1, w1s1)

  // C/D layout: col = lane&15, row = (lane>>4)*4 + j  (verified R2)
  // Agent-scope stores (IC coherence point) so the closing block of this
  // row-group can read them from any XCD (G16-compliant).
  const int m0 = mt * 32, n0 = nt * 32;
  const int col = lane & 15;
  const int rg = (lane >> 4) * 4;
  const float bv0 = bias[n0 + col];
  const float bv1 = bias[n0 + 16 + col];
#pragma unroll
  for (int j = 0; j < 4; ++j) {
    const int r = rg + j;
    __hip_atomic_store(&C[(size_t)(m0 + r) * N_ + n0 + col], acc00[j] + bv0,
                       __ATOMIC_RELAXED, __HIP_MEMORY_SCOPE_AGENT);
    __hip_atomic_store(&C[(size_t)(m0 + r) * N_ + n0 + 16 + col], acc01[j] + bv1,
                       __ATOMIC_RELAXED, __HIP_MEMORY_SCOPE_AGENT);
    __hip_atomic_store(&C[(size_t)(m0 + 16 + r) * N_ + n0 + col], acc10[j] + bv0,
                       __ATOMIC_RELAXED, __HIP_MEMORY_SCOPE_AGENT);
    __hip_atomic_store(&C[(size_t)(m0 + 16 + r) * N_ + n0 + 16 + col], acc11[j] + bv1,
                       __ATOMIC_RELAXED, __HIP_MEMORY_SCOPE_AGENT);
  }
}

__global__ __launch_bounds__(256) void gemm_norm_kernel(
    const __hip_bfloat16* __restrict__ A1f, const __hip_bfloat16* __restrict__ A2f,
    const __hip_bfloat16* __restrict__ W1f, const __hip_bfloat16* __restrict__ W2f,
    const float* __restrict__ b1, const float* __restrict__ b2,
    float* __restrict__ out, int* __restrict__ cnt) {
  // 192 blocks x 256 thr; block tile 64x64 = 2x2 waves of 32x32 (R8 mapping).
  const int bid = blockIdx.x;
  const int x = bid & 7;
  const int local = bid >> 3;           // 0..23
  const int ntb_g = x * 3 + local % 3;  // 0..23 global block-column
  const int mtb = local / 3;            // 0..7
  const int wid = threadIdx.x >> 6;     // 0..3
  const int lane = threadIdx.x & 63;
  const int wr = wid >> 1, wc = wid & 1;
  const int mt = mtb * 2 + wr;          // 32-row tile index
  const bool g2 = (ntb_g >= 12);
  float* Cg = g2 ? out + (size_t)M_ * N_ : out;
  if (!g2) {
    const int nt = ntb_g * 2 + wc;
    gemm_body<NK1>((const bf16x8v*)A1f, (const bf16x8v*)W1f, b1, Cg, mt, nt);
  } else {
    const int nt = (ntb_g - 12) * 2 + wc;
    gemm_body<NK2>((const bf16x8v*)A2f, (const bf16x8v*)W2f, b2, Cg, mt, nt);
  }

  // ---- row-group completion: counter per (gemm, mtb) = 64 rows x 12 blocks
  __shared__ int sdone;
  asm volatile("s_waitcnt vmcnt(0)" ::: "memory");  // our sc-stores at IC
  __syncthreads();
  const int rgid = (g2 ? 8 : 0) + mtb;
  if (threadIdx.x == 0) {
    int prev = __hip_atomic_fetch_add(&cnt[rgid], 1, __ATOMIC_RELAXED,
                                      __HIP_MEMORY_SCOPE_AGENT);
    sdone = (prev == 11);
  }
  __syncthreads();
  if (!sdone) return;

  // ---- last block of this row-group: normalize its 64 rows ----
  // wave wid handles rows [mtb*64 + wid*16, +16); per row: col = e*64+lane.
  const int r0 = mtb * 64 + wid * 16;
  for (int rr = 0; rr < 16; ++rr) {
    float* p = Cg + (size_t)(r0 + rr) * N_;
    float v[12];
    float ss = 0.f;
#pragma unroll
    for (int e = 0; e < 12; ++e) {
      v[e] = __hip_atomic_load(&p[e * 64 + lane], __ATOMIC_RELAXED,
                               __HIP_MEMORY_SCOPE_AGENT);
      ss += v[e] * v[e];
    }
#pragma unroll
    for (int off = 32; off > 0; off >>= 1) ss += __shfl_xor(ss, off);
    const float inv = 1.0f / fmaxf(sqrtf(ss), 1e-12f);
#pragma unroll
    for (int e = 0; e < 12; ++e) p[e * 64 + lane] = v[e] * inv;
  }
}

// ---------------------------------------------------------------------------
extern "C" void kernel_launch(void* const* d_in, const int* in_sizes, int n_in,
                              void* d_out, int out_size, void* d_ws, size_t ws_size,
                              hipStream_t stream) {
  const float* phys  = (const float*)d_in[0];
  const float* proc  = (const float*)d_in[1];
  const float* micro = (const float*)d_in[2];
  const int*   pos   = (const int*)d_in[3];
  const float* W1    = (const float*)d_in[4];
  const float* b1    = (const float*)d_in[5];
  const float* W2    = (const float*)d_in[6];
  const float* b2    = (const float*)d_in[7];
  float* out = (float*)d_out;

  // ws layout (bf16): A1f | A2f | W1f | W2f | counters (~9.4 MB + 64 B)
  __hip_bfloat16* A1f = (__hip_bfloat16*)d_ws;
  __hip_bfloat16* A2f = A1f + (size_t)32 * NK1 * 512;
  __hip_bfloat16* W1f = A2f + (size_t)32 * NK2 * 512;
  __hip_bfloat16* W2f = W1f + (size_t)48 * NK1 * 512;
  int* cnt = (int*)(W2f + (size_t)48 * NK2 * 512);

  pool_cvt_kernel<<<2 * B_ + CVT_BLOCKS, 192, 0, stream>>>(
      phys, proc, micro, pos, W1, W2, A1f, A2f, W1f, W2f, cnt);
  gemm_norm_kernel<<<192, 256, 0, stream>>>(
      A1f, A2f, W1f, W2f, b1, b2, out, cnt);
}

// Round 12
// 47.180 us; speedup vs baseline: 5.8435x; 1.0839x over previous
//
#include <hip/hip_runtime.h>
#include <hip/hip_bf16.h>

// Problem constants (B,S,H,P) = (512, 256, 768, 32)
#define B_  512
#define S_  256
#define H_  768
#define P_  32
#define K1_ 2304   // 3H
#define K2_ 1536   // 2H
#define N_  768
#define M_  512
#define NK1 72     // K1/32
#define NK2 48     // K2/32
#define CVT_BLOCKS 512

typedef __attribute__((ext_vector_type(8))) short bf16x8v;
typedef __attribute__((ext_vector_type(8))) unsigned short u16x8;
typedef __attribute__((ext_vector_type(4))) float f32x4v;

__device__ inline unsigned short bfb(float x) {
  __hip_bfloat16 h = __float2bfloat16(x);  // RNE
  return *reinterpret_cast<unsigned short*>(&h);
}

// Fragment layout (bf16), MFMA 16x16x32 operand order (proven R2/R3):
//   frag[t16][k32][lane][8], lane = kg*16 + r; element (t,k):
//   t = t16*16 + r, k = k32*32 + kg*8 + e.
__device__ inline void store4_frag(__hip_bfloat16* __restrict__ buf, int NK,
                                   int m, int k, float4 v) {
  int m16 = m >> 4, mr = m & 15, k32 = k >> 5, kg = (k >> 3) & 3, e = k & 7;
  size_t off = ((size_t)(m16 * NK + k32) * 64 + kg * 16 + mr) * 8 + e;
  ushort4 u;
  u.x = bfb(v.x); u.y = bfb(v.y); u.z = bfb(v.z); u.w = bfb(v.w);
  *reinterpret_cast<ushort4*>(buf + off) = u;
}

// one 16B fragment-group of W conversion (fp32 row-major [n][k] -> B-frag)
__device__ inline void cvt_one(const float* __restrict__ W,
                               __hip_bfloat16* __restrict__ Wf,
                               int NK, int K, int gg) {
  int lane = gg & 63;
  int rest = gg >> 6;
  int k32 = rest % NK;
  int n16 = rest / NK;
  int n = n16 * 16 + (lane & 15);
  int k = k32 * 32 + (lane >> 4) * 8;
  const float4* sW = (const float4*)(W + (size_t)n * K + k);
  float4 v0 = sW[0], v1 = sW[1];
  u16x8 o;
  o[0] = bfb(v0.x); o[1] = bfb(v0.y); o[2] = bfb(v0.z); o[3] = bfb(v0.w);
  o[4] = bfb(v1.x); o[5] = bfb(v1.y); o[6] = bfb(v1.z); o[7] = bfb(v1.w);
  *reinterpret_cast<u16x8*>(Wf + (size_t)gg * 8) = o;
}

// ---------------------------------------------------------------------------
// Kernel 1 (R8, unchanged): blocks [0,2B): (batch,tensor) mean-pool -> A-frag.
// blocks [2B,2B+CVT_BLOCKS): W cvt (grid-stride).
// ---------------------------------------------------------------------------
__global__ __launch_bounds__(192) void pool_cvt_kernel(
    const float* __restrict__ phys, const float* __restrict__ proc,
    const float* __restrict__ micro, const int* __restrict__ pos,
    const float* __restrict__ W1, const float* __restrict__ W2,
    __hip_bfloat16* __restrict__ A1f, __hip_bfloat16* __restrict__ A2f,
    __hip_bfloat16* __restrict__ W1f, __hip_bfloat16* __restrict__ W2f) {
  const int t = threadIdx.x;  // 0..191
  const int NPOOL = 2 * B_;   // 1024
  if (blockIdx.x < NPOOL) {
    const int bid = blockIdx.x;
    const int b   = bid >> 1;
    const int sel = bid & 1;

    __shared__ int sp[P_];
    __shared__ int scnt;
    if (t < 64) {
      int p = (t < P_) ? pos[b * P_ + t] : -1;
      bool valid = (p != -1);
      unsigned long long m = __ballot(valid);
      int pre = __popcll(m & ((1ull << t) - 1ull));
      if (valid) sp[pre] = p;
      if (t == 0) scnt = (int)__popcll(m);
    }
    __syncthreads();
    const int c = scnt;  // >= 1
    const float inv = 1.0f / (float)c;

    const int H4 = H_ / 4;
    const float* base = (sel == 0) ? proc : micro;
    const float4* srcb = (const float4*)(base + (size_t)b * S_ * H_);

    float4 sent = srcb[t];
    float4 sph = make_float4(0.f, 0.f, 0.f, 0.f);
    if (sel == 0) sph = ((const float4*)(phys + (size_t)b * S_ * H_))[t];

    float4 s0 = make_float4(0.f, 0.f, 0.f, 0.f);
    float4 s1 = make_float4(0.f, 0.f, 0.f, 0.f);
    int i = 0;
    for (; i + 8 <= c; i += 8) {
      float4 v0 = srcb[(size_t)sp[i+0] * H4 + t];
      float4 v1 = srcb[(size_t)sp[i+1] * H4 + t];
      float4 v2 = srcb[(size_t)sp[i+2] * H4 + t];
      float4 v3 = srcb[(size_t)sp[i+3] * H4 + t];
      float4 v4 = srcb[(size_t)sp[i+4] * H4 + t];
      float4 v5 = srcb[(size_t)sp[i+5] * H4 + t];
      float4 v6 = srcb[(size_t)sp[i+6] * H4 + t];
      float4 v7 = srcb[(size_t)sp[i+7] * H4 + t];
      s0.x += v0.x + v1.x + v2.x + v3.x;  s1.x += v4.x + v5.x + v6.x + v7.x;
      s0.y += v0.y + v1.y + v2.y + v3.y;  s1.y += v4.y + v5.y + v6.y + v7.y;
      s0.z += v0.z + v1.z + v2.z + v3.z;  s1.z += v4.z + v5.z + v6.z + v7.z;
      s0.w += v0.w + v1.w + v2.w + v3.w;  s1.w += v4.w + v5.w + v6.w + v7.w;
    }
    for (; i + 2 <= c; i += 2) {
      float4 v0 = srcb[(size_t)sp[i+0] * H4 + t];
      float4 v1 = srcb[(size_t)sp[i+1] * H4 + t];
      s0.x += v0.x + v1.x; s0.y += v0.y + v1.y;
      s0.z += v0.z + v1.z; s0.w += v0.w + v1.w;
    }
    if (i < c) {
      float4 v = srcb[(size_t)sp[i] * H4 + t];
      s0.x += v.x; s0.y += v.y; s0.z += v.z; s0.w += v.w;
    }
    float4 pooled = make_float4((s0.x + s1.x) * inv, (s0.y + s1.y) * inv,
                                (s0.z + s1.z) * inv, (s0.w + s1.w) * inv);

    const int k = t * 4;
    if (sel == 0) {
      store4_frag(A1f, NK1, b, k,          pooled);
      store4_frag(A1f, NK1, b, k + H_,     sent);
      store4_frag(A1f, NK1, b, k + 2*H_,   sph);
    } else {
      store4_frag(A2f, NK2, b, k,          pooled);
      store4_frag(A2f, NK2, b, k + H_,     sent);
    }
  } else {
    const int NG1 = 48 * NK1 * 64;
    const int NG2 = 48 * NK2 * 64;
    int tid = (blockIdx.x - NPOOL) * 192 + t;
    const int stride = CVT_BLOCKS * 192;
    for (int g = tid; g < NG1 + NG2; g += stride) {
      if (g < NG1) cvt_one(W1, W1f, NK1, K1_, g);
      else         cvt_one(W2, W2f, NK2, K2_, g - NG1);
    }
  }
}

// ---------------------------------------------------------------------------
// Kernel 2: dual bf16 MFMA GEMM. 384 x 2-wave blocks: wave pair shares the
// same A-frag rows (tile 32x64) -> L1 catches the duplicate A loads, and
// 384 blocks cover all 256 CUs (R8 used only 192 CUs). Inner loop = proven
// R3/R8 body with distance-2 register prefetch.
// ---------------------------------------------------------------------------
#define MFMA4(A0V, A1V, W0V, W1V)                                             \
  acc00 = __builtin_amdgcn_mfma_f32_16x16x32_bf16(A0V, W0V, acc00, 0, 0, 0);  \
  acc01 = __builtin_amdgcn_mfma_f32_16x16x32_bf16(A0V, W1V, acc01, 0, 0, 0);  \
  acc10 = __builtin_amdgcn_mfma_f32_16x16x32_bf16(A1V, W0V, acc10, 0, 0, 0);  \
  acc11 = __builtin_amdgcn_mfma_f32_16x16x32_bf16(A1V, W1V, acc11, 0, 0, 0);

template <int NK>
__device__ inline void gemm_body(const bf16x8v* __restrict__ Af,
                                 const bf16x8v* __restrict__ Wf,
                                 const float* __restrict__ bias,
                                 float* __restrict__ C, int mt, int nt) {
  const int lane = threadIdx.x & 63;

  const bf16x8v* A0 = Af + (size_t)(2 * mt) * NK * 64 + lane;
  const bf16x8v* A1 = A0 + (size_t)NK * 64;
  const bf16x8v* B0 = Wf + (size_t)(2 * nt) * NK * 64 + lane;
  const bf16x8v* B1 = B0 + (size_t)NK * 64;

  f32x4v acc00 = {0.f, 0.f, 0.f, 0.f};
  f32x4v acc01 = {0.f, 0.f, 0.f, 0.f};
  f32x4v acc10 = {0.f, 0.f, 0.f, 0.f};
  f32x4v acc11 = {0.f, 0.f, 0.f, 0.f};

  bf16x8v a0s0 = A0[0],  a1s0 = A1[0],  w0s0 = B0[0],  w1s0 = B1[0];
  bf16x8v a0s1 = A0[64], a1s1 = A1[64], w0s1 = B0[64], w1s1 = B1[64];

  for (int k = 0; k < NK - 2; k += 2) {
    bf16x8v pa0 = A0[(size_t)(k + 2) * 64];
    bf16x8v pa1 = A1[(size_t)(k + 2) * 64];
    bf16x8v pw0 = B0[(size_t)(k + 2) * 64];
    bf16x8v pw1 = B1[(size_t)(k + 2) * 64];
    bf16x8v qa0 = A0[(size_t)(k + 3) * 64];
    bf16x8v qa1 = A1[(size_t)(k + 3) * 64];
    bf16x8v qw0 = B0[(size_t)(k + 3) * 64];
    bf16x8v qw1 = B1[(size_t)(k + 3) * 64];
    MFMA4(a0s0, a1s0, w0s0, w1s0)
    MFMA4(a0s1, a1s1, w0s1, w1s1)
    a0s0 = pa0; a1s0 = pa1; w0s0 = pw0; w1s0 = pw1;
    a0s1 = qa0; a1s1 = qa1; w0s1 = qw0; w1s1 = qw1;
  }
  MFMA4(a0s0, a1s0, w0s0, w1s0)
  MFMA4(a0s1, a1s1, w0s1, w1s1)

  // C/D layout: col = lane&15, row = (lane>>4)*4 + j  (verified R2)
  const int m0 = mt * 32, n0 = nt * 32;
  const int col = lane & 15;
  const int rg = (lane >> 4) * 4;
  const float bv0 = bias[n0 + col];
  const float bv1 = bias[n0 + 16 + col];
#pragma unroll
  for (int j = 0; j < 4; ++j) {
    const int r = rg + j;
    C[(size_t)(m0 + r) * N_ + n0 + col]           = acc00[j] + bv0;
    C[(size_t)(m0 + r) * N_ + n0 + 16 + col]      = acc01[j] + bv1;
    C[(size_t)(m0 + 16 + r) * N_ + n0 + col]      = acc10[j] + bv0;
    C[(size_t)(m0 + 16 + r) * N_ + n0 + 16 + col] = acc11[j] + bv1;
  }
}

__global__ __launch_bounds__(128) void gemm_mfma_kernel(
    const __hip_bfloat16* __restrict__ A1f, const __hip_bfloat16* __restrict__ A2f,
    const __hip_bfloat16* __restrict__ W1f, const __hip_bfloat16* __restrict__ W2f,
    const float* __restrict__ b1, const float* __restrict__ b2,
    float* __restrict__ out) {
  // 384 blocks x 128 thr (2 waves). Block tile 32x64: wave w -> nt = ntp*2+w,
  // same mt (waves share A-frag rows -> L1 hit on the duplicate load).
  // Parity-interleave GEMM1/GEMM2 across consecutive bids (spreads XCDs).
  const int bid = blockIdx.x;
  const int sel = bid & 1;
  const int tl = bid >> 1;          // 0..191
  const int mt = tl / 12;           // 0..15
  const int ntp = tl % 12;          // 0..11
  const int w = threadIdx.x >> 6;   // 0..1
  const int nt = ntp * 2 + w;       // 0..23
  if (sel == 0) {
    gemm_body<NK1>((const bf16x8v*)A1f, (const bf16x8v*)W1f, b1, out, mt, nt);
  } else {
    gemm_body<NK2>((const bf16x8v*)A2f, (const bf16x8v*)W2f, b2,
                   out + (size_t)M_ * N_, mt, nt);
  }
}

// ---------------------------------------------------------------------------
// Kernel 3: in-place row L2 normalization (vectorized float4: 192 thr/row).
// ---------------------------------------------------------------------------
__global__ __launch_bounds__(192) void norm_rows_kernel(float* __restrict__ out) {
  const int row = blockIdx.x;  // 0..1023
  float4* p = (float4*)(out + (size_t)row * N_);
  const int t = threadIdx.x;   // 0..191
  float4 v = p[t];
  float s = v.x * v.x + v.y * v.y + v.z * v.z + v.w * v.w;
#pragma unroll
  for (int off = 32; off > 0; off >>= 1) s += __shfl_down(s, off);
  __shared__ float ws[3];
  const int lane = t & 63, wid = t >> 6;
  if (lane == 0) ws[wid] = s;
  __syncthreads();
  float tot = ws[0] + ws[1] + ws[2];
  float inv = 1.0f / fmaxf(sqrtf(tot), 1e-12f);
  v.x *= inv; v.y *= inv; v.z *= inv; v.w *= inv;
  p[t] = v;
}

// ---------------------------------------------------------------------------
extern "C" void kernel_launch(void* const* d_in, const int* in_sizes, int n_in,
                              void* d_out, int out_size, void* d_ws, size_t ws_size,
                              hipStream_t stream) {
  const float* phys  = (const float*)d_in[0];
  const float* proc  = (const float*)d_in[1];
  const float* micro = (const float*)d_in[2];
  const int*   pos   = (const int*)d_in[3];
  const float* W1    = (const float*)d_in[4];
  const float* b1    = (const float*)d_in[5];
  const float* W2    = (const float*)d_in[6];
  const float* b2    = (const float*)d_in[7];
  float* out = (float*)d_out;

  // ws layout (bf16): A1f | A2f | W1f | W2f  (~9.4 MB)
  __hip_bfloat16* A1f = (__hip_bfloat16*)d_ws;
  __hip_bfloat16* A2f = A1f + (size_t)32 * NK1 * 512;
  __hip_bfloat16* W1f = A2f + (size_t)32 * NK2 * 512;
  __hip_bfloat16* W2f = W1f + (size_t)48 * NK1 * 512;

  pool_cvt_kernel<<<2 * B_ + CVT_BLOCKS, 192, 0, stream>>>(
      phys, proc, micro, pos, W1, W2, A1f, A2f, W1f, W2f);
  gemm_mfma_kernel<<<384, 128, 0, stream>>>(
      A1f, A2f, W1f, W2f, b1, b2, out);
  norm_rows_kernel<<<2 * B_, 192, 0, stream>>>(out);
}

// Round 13
// 46.687 us; speedup vs baseline: 5.9053x; 1.0106x over previous
//
#include <hip/hip_runtime.h>
#include <hip/hip_bf16.h>

// Problem constants (B,S,H,P) = (512, 256, 768, 32)
#define B_  512
#define S_  256
#define H_  768
#define P_  32
#define K1_ 2304   // 3H
#define K2_ 1536   // 2H
#define N_  768
#define M_  512
#define NK1 72     // K1/32
#define NK2 48     // K2/32
#define CVT_BLOCKS 512

typedef __attribute__((ext_vector_type(8))) short bf16x8v;
typedef __attribute__((ext_vector_type(8))) unsigned short u16x8;
typedef __attribute__((ext_vector_type(4))) float f32x4v;

__device__ inline unsigned short bfb(float x) {
  __hip_bfloat16 h = __float2bfloat16(x);  // RNE
  return *reinterpret_cast<unsigned short*>(&h);
}

// Fragment layout (bf16), MFMA 16x16x32 operand order (proven R2/R3):
//   frag[t16][k32][lane][8], lane = kg*16 + r; element (t,k):
//   t = t16*16 + r, k = k32*32 + kg*8 + e.
__device__ inline void store4_frag(__hip_bfloat16* __restrict__ buf, int NK,
                                   int m, int k, float4 v) {
  int m16 = m >> 4, mr = m & 15, k32 = k >> 5, kg = (k >> 3) & 3, e = k & 7;
  size_t off = ((size_t)(m16 * NK + k32) * 64 + kg * 16 + mr) * 8 + e;
  ushort4 u;
  u.x = bfb(v.x); u.y = bfb(v.y); u.z = bfb(v.z); u.w = bfb(v.w);
  *reinterpret_cast<ushort4*>(buf + off) = u;
}

// one 16B fragment-group of W conversion (fp32 row-major [n][k] -> B-frag)
__device__ inline void cvt_one(const float* __restrict__ W,
                               __hip_bfloat16* __restrict__ Wf,
                               int NK, int K, int gg) {
  int lane = gg & 63;
  int rest = gg >> 6;
  int k32 = rest % NK;
  int n16 = rest / NK;
  int n = n16 * 16 + (lane & 15);
  int k = k32 * 32 + (lane >> 4) * 8;
  const float4* sW = (const float4*)(W + (size_t)n * K + k);
  float4 v0 = sW[0], v1 = sW[1];
  u16x8 o;
  o[0] = bfb(v0.x); o[1] = bfb(v0.y); o[2] = bfb(v0.z); o[3] = bfb(v0.w);
  o[4] = bfb(v1.x); o[5] = bfb(v1.y); o[6] = bfb(v1.z); o[7] = bfb(v1.w);
  *reinterpret_cast<u16x8*>(Wf + (size_t)gg * 8) = o;
}

// ---------------------------------------------------------------------------
// Kernel 1 (R8, unchanged): blocks [0,2B): (batch,tensor) mean-pool -> A-frag.
// blocks [2B,2B+CVT_BLOCKS): W cvt (grid-stride).
// ---------------------------------------------------------------------------
__global__ __launch_bounds__(192) void pool_cvt_kernel(
    const float* __restrict__ phys, const float* __restrict__ proc,
    const float* __restrict__ micro, const int* __restrict__ pos,
    const float* __restrict__ W1, const float* __restrict__ W2,
    __hip_bfloat16* __restrict__ A1f, __hip_bfloat16* __restrict__ A2f,
    __hip_bfloat16* __restrict__ W1f, __hip_bfloat16* __restrict__ W2f) {
  const int t = threadIdx.x;  // 0..191
  const int NPOOL = 2 * B_;   // 1024
  if (blockIdx.x < NPOOL) {
    const int bid = blockIdx.x;
    const int b   = bid >> 1;
    const int sel = bid & 1;

    __shared__ int sp[P_];
    __shared__ int scnt;
    if (t < 64) {
      int p = (t < P_) ? pos[b * P_ + t] : -1;
      bool valid = (p != -1);
      unsigned long long m = __ballot(valid);
      int pre = __popcll(m & ((1ull << t) - 1ull));
      if (valid) sp[pre] = p;
      if (t == 0) scnt = (int)__popcll(m);
    }
    __syncthreads();
    const int c = scnt;  // >= 1
    const float inv = 1.0f / (float)c;

    const int H4 = H_ / 4;
    const float* base = (sel == 0) ? proc : micro;
    const float4* srcb = (const float4*)(base + (size_t)b * S_ * H_);

    float4 sent = srcb[t];
    float4 sph = make_float4(0.f, 0.f, 0.f, 0.f);
    if (sel == 0) sph = ((const float4*)(phys + (size_t)b * S_ * H_))[t];

    float4 s0 = make_float4(0.f, 0.f, 0.f, 0.f);
    float4 s1 = make_float4(0.f, 0.f, 0.f, 0.f);
    int i = 0;
    for (; i + 8 <= c; i += 8) {
      float4 v0 = srcb[(size_t)sp[i+0] * H4 + t];
      float4 v1 = srcb[(size_t)sp[i+1] * H4 + t];
      float4 v2 = srcb[(size_t)sp[i+2] * H4 + t];
      float4 v3 = srcb[(size_t)sp[i+3] * H4 + t];
      float4 v4 = srcb[(size_t)sp[i+4] * H4 + t];
      float4 v5 = srcb[(size_t)sp[i+5] * H4 + t];
      float4 v6 = srcb[(size_t)sp[i+6] * H4 + t];
      float4 v7 = srcb[(size_t)sp[i+7] * H4 + t];
      s0.x += v0.x + v1.x + v2.x + v3.x;  s1.x += v4.x + v5.x + v6.x + v7.x;
      s0.y += v0.y + v1.y + v2.y + v3.y;  s1.y += v4.y + v5.y + v6.y + v7.y;
      s0.z += v0.z + v1.z + v2.z + v3.z;  s1.z += v4.z + v5.z + v6.z + v7.z;
      s0.w += v0.w + v1.w + v2.w + v3.w;  s1.w += v4.w + v5.w + v6.w + v7.w;
    }
    for (; i + 2 <= c; i += 2) {
      float4 v0 = srcb[(size_t)sp[i+0] * H4 + t];
      float4 v1 = srcb[(size_t)sp[i+1] * H4 + t];
      s0.x += v0.x + v1.x; s0.y += v0.y + v1.y;
      s0.z += v0.z + v1.z; s0.w += v0.w + v1.w;
    }
    if (i < c) {
      float4 v = srcb[(size_t)sp[i] * H4 + t];
      s0.x += v.x; s0.y += v.y; s0.z += v.z; s0.w += v.w;
    }
    float4 pooled = make_float4((s0.x + s1.x) * inv, (s0.y + s1.y) * inv,
                                (s0.z + s1.z) * inv, (s0.w + s1.w) * inv);

    const int k = t * 4;
    if (sel == 0) {
      store4_frag(A1f, NK1, b, k,          pooled);
      store4_frag(A1f, NK1, b, k + H_,     sent);
      store4_frag(A1f, NK1, b, k + 2*H_,   sph);
    } else {
      store4_frag(A2f, NK2, b, k,          pooled);
      store4_frag(A2f, NK2, b, k + H_,     sent);
    }
  } else {
    const int NG1 = 48 * NK1 * 64;
    const int NG2 = 48 * NK2 * 64;
    int tid = (blockIdx.x - NPOOL) * 192 + t;
    const int stride = CVT_BLOCKS * 192;
    for (int g = tid; g < NG1 + NG2; g += stride) {
      if (g < NG1) cvt_one(W1, W1f, NK1, K1_, g);
      else         cvt_one(W2, W2f, NK2, K2_, g - NG1);
    }
  }
}

// ---------------------------------------------------------------------------
// Kernel 2 (R8, unchanged): dual bf16 MFMA GEMM. 192 blocks x 256 thr,
// 64x64 block tile = 2x2 waves of 32x32; frag operands; d2 prefetch;
// XCD column swizzle (XCD x owns 3 of 24 block-columns, ~3.4 MB < 4 MB L2).
// ---------------------------------------------------------------------------
#define MFMA4(A0V, A1V, W0V, W1V)                                             \
  acc00 = __builtin_amdgcn_mfma_f32_16x16x32_bf16(A0V, W0V, acc00, 0, 0, 0);  \
  acc01 = __builtin_amdgcn_mfma_f32_16x16x32_bf16(A0V, W1V, acc01, 0, 0, 0);  \
  acc10 = __builtin_amdgcn_mfma_f32_16x16x32_bf16(A1V, W0V, acc10, 0, 0, 0);  \
  acc11 = __builtin_amdgcn_mfma_f32_16x16x32_bf16(A1V, W1V, acc11, 0, 0, 0);

template <int NK>
__device__ inline void gemm_body(const bf16x8v* __restrict__ Af,
                                 const bf16x8v* __restrict__ Wf,
                                 const float* __restrict__ bias,
                                 float* __restrict__ C, int mt, int nt) {
  const int lane = threadIdx.x & 63;

  const bf16x8v* A0 = Af + (size_t)(2 * mt) * NK * 64 + lane;
  const bf16x8v* A1 = A0 + (size_t)NK * 64;
  const bf16x8v* B0 = Wf + (size_t)(2 * nt) * NK * 64 + lane;
  const bf16x8v* B1 = B0 + (size_t)NK * 64;

  f32x4v acc00 = {0.f, 0.f, 0.f, 0.f};
  f32x4v acc01 = {0.f, 0.f, 0.f, 0.f};
  f32x4v acc10 = {0.f, 0.f, 0.f, 0.f};
  f32x4v acc11 = {0.f, 0.f, 0.f, 0.f};

  bf16x8v a0s0 = A0[0],  a1s0 = A1[0],  w0s0 = B0[0],  w1s0 = B1[0];
  bf16x8v a0s1 = A0[64], a1s1 = A1[64], w0s1 = B0[64], w1s1 = B1[64];

  for (int k = 0; k < NK - 2; k += 2) {
    bf16x8v pa0 = A0[(size_t)(k + 2) * 64];
    bf16x8v pa1 = A1[(size_t)(k + 2) * 64];
    bf16x8v pw0 = B0[(size_t)(k + 2) * 64];
    bf16x8v pw1 = B1[(size_t)(k + 2) * 64];
    bf16x8v qa0 = A0[(size_t)(k + 3) * 64];
    bf16x8v qa1 = A1[(size_t)(k + 3) * 64];
    bf16x8v qw0 = B0[(size_t)(k + 3) * 64];
    bf16x8v qw1 = B1[(size_t)(k + 3) * 64];
    MFMA4(a0s0, a1s0, w0s0, w1s0)
    MFMA4(a0s1, a1s1, w0s1, w1s1)
    a0s0 = pa0; a1s0 = pa1; w0s0 = pw0; w1s0 = pw1;
    a0s1 = qa0; a1s1 = qa1; w0s1 = qw0; w1s1 = qw1;
  }
  MFMA4(a0s0, a1s0, w0s0, w1s0)
  MFMA4(a0s1, a1s1, w0s1, w1s1)

  // C/D layout: col = lane&15, row = (lane>>4)*4 + j  (verified R2)
  const int m0 = mt * 32, n0 = nt * 32;
  const int col = lane & 15;
  const int rg = (lane >> 4) * 4;
  const float bv0 = bias[n0 + col];
  const float bv1 = bias[n0 + 16 + col];
#pragma unroll
  for (int j = 0; j < 4; ++j) {
    const int r = rg + j;
    C[(size_t)(m0 + r) * N_ + n0 + col]           = acc00[j] + bv0;
    C[(size_t)(m0 + r) * N_ + n0 + 16 + col]      = acc01[j] + bv1;
    C[(size_t)(m0 + 16 + r) * N_ + n0 + col]      = acc10[j] + bv0;
    C[(size_t)(m0 + 16 + r) * N_ + n0 + 16 + col] = acc11[j] + bv1;
  }
}

__global__ __launch_bounds__(256) void gemm_mfma_kernel(
    const __hip_bfloat16* __restrict__ A1f, const __hip_bfloat16* __restrict__ A2f,
    const __hip_bfloat16* __restrict__ W1f, const __hip_bfloat16* __restrict__ W2f,
    const float* __restrict__ b1, const float* __restrict__ b2,
    float* __restrict__ out) {
  // 192 blocks x 256 thr. Block tile 64x64 = 2x2 waves of 32x32.
  // XCD x (bid&7) owns 3 consecutive of the 24 block-columns (2 GEMMs x 12).
  const int bid = blockIdx.x;
  const int x = bid & 7;
  const int local = bid >> 3;           // 0..23
  const int ntb_g = x * 3 + local % 3;  // 0..23 global block-column
  const int mtb = local / 3;            // 0..7
  const int wid = threadIdx.x >> 6;     // 0..3
  const int wr = wid >> 1, wc = wid & 1;
  const int mt = mtb * 2 + wr;          // 0..15 (32-row tile)
  if (ntb_g < 12) {
    const int nt = ntb_g * 2 + wc;      // 0..23
    gemm_body<NK1>((const bf16x8v*)A1f, (const bf16x8v*)W1f, b1, out, mt, nt);
  } else {
    const int nt = (ntb_g - 12) * 2 + wc;
    gemm_body<NK2>((const bf16x8v*)A2f, (const bf16x8v*)W2f, b2,
                   out + (size_t)M_ * N_, mt, nt);
  }
}

// ---------------------------------------------------------------------------
// Kernel 3: in-place row L2 normalization (vectorized float4: 192 thr/row).
// ---------------------------------------------------------------------------
__global__ __launch_bounds__(192) void norm_rows_kernel(float* __restrict__ out) {
  const int row = blockIdx.x;  // 0..1023
  float4* p = (float4*)(out + (size_t)row * N_);
  const int t = threadIdx.x;   // 0..191
  float4 v = p[t];
  float s = v.x * v.x + v.y * v.y + v.z * v.z + v.w * v.w;
#pragma unroll
  for (int off = 32; off > 0; off >>= 1) s += __shfl_down(s, off);
  __shared__ float ws[3];
  const int lane = t & 63, wid = t >> 6;
  if (lane == 0) ws[wid] = s;
  __syncthreads();
  float tot = ws[0] + ws[1] + ws[2];
  float inv = 1.0f / fmaxf(sqrtf(tot), 1e-12f);
  v.x *= inv; v.y *= inv; v.z *= inv; v.w *= inv;
  p[t] = v;
}

// ---------------------------------------------------------------------------
extern "C" void kernel_launch(void* const* d_in, const int* in_sizes, int n_in,
                              void* d_out, int out_size, void* d_ws, size_t ws_size,
                              hipStream_t stream) {
  const float* phys  = (const float*)d_in[0];
  const float* proc  = (const float*)d_in[1];
  const float* micro = (const float*)d_in[2];
  const int*   pos   = (const int*)d_in[3];
  const float* W1    = (const float*)d_in[4];
  const float* b1    = (const float*)d_in[5];
  const float* W2    = (const float*)d_in[6];
  const float* b2    = (const float*)d_in[7];
  float* out = (float*)d_out;

  // ws layout (bf16): A1f | A2f | W1f | W2f  (~9.4 MB)
  __hip_bfloat16* A1f = (__hip_bfloat16*)d_ws;
  __hip_bfloat16* A2f = A1f + (size_t)32 * NK1 * 512;
  __hip_bfloat16* W1f = A2f + (size_t)32 * NK2 * 512;
  __hip_bfloat16* W2f = W1f + (size_t)48 * NK1 * 512;

  pool_cvt_kernel<<<2 * B_ + CVT_BLOCKS, 192, 0, stream>>>(
      phys, proc, micro, pos, W1, W2, A1f, A2f, W1f, W2f);
  gemm_mfma_kernel<<<192, 256, 0, stream>>>(
      A1f, A2f, W1f, W2f, b1, b2, out);
  norm_rows_kernel<<<2 * B_, 192, 0, stream>>>(out);
}